// Round 2
// baseline (538.262 us; speedup 1.0000x reference)
//
#include <hip/hip_runtime.h>

// ---------- types ----------
typedef unsigned short u16;
typedef unsigned int   u32;
typedef __attribute__((ext_vector_type(4))) float f32x4;
typedef __attribute__((ext_vector_type(8))) __bf16 bf16x8;
typedef __attribute__((ext_vector_type(4))) u32  u32x4;

#define LDS_CAST(p) ((__attribute__((address_space(3))) void*)(p))
#define GLB_CAST(p) ((const __attribute__((address_space(1))) void*)(p))

__device__ __forceinline__ void load_lds16(const void* g, void* l) {
    __builtin_amdgcn_global_load_lds(GLB_CAST(g), LDS_CAST(l), 16, 0, 0);
}

__device__ __forceinline__ u16 f2bf(float f) {
    union { float f; u32 u; } v; v.f = f;
    u32 r = (v.u + 0x7FFFu + ((v.u >> 16) & 1u)) >> 16;
    return (u16)r;
}

// ---------- constants ----------
// B=4, T=2048, E=1024, H=16, hd=64, M = B*T = 8192
// ws layout (bytes):
//  [0,8MB)    : Wq,Wk,Wv,Wo bf16 (2MB each)
//  [8,24MB)   : x bf16
//  [24,40MB)  : rx bf16
//  [40,56MB)  : Q (B,H,T,64) bf16
//  [56,72MB)  : K
//  [72,88MB)  : V
//  [88,104MB) : O (B*T, 1024) bf16

// ---------- kernel 1: RoPE + cast ----------
__global__ __launch_bounds__(256) void rope_cast(const float* __restrict__ x,
                                                 u16* __restrict__ xb,
                                                 u16* __restrict__ rxb) {
    int idx = blockIdx.x * 256 + threadIdx.x;      // one pair, total 4194304
    int e2 = (idx & 511) * 2;                      // even element index within E
    int t  = (idx >> 9) & 2047;
    float2 v = *(const float2*)&x[(size_t)idx * 2];
    // theta = 10000^(-e2/1024) = exp(-ln(10000)/1024 * e2)
    float theta = expf(-0.0089944730194981f * (float)e2);
    float angle = (float)t * theta;
    float sa, ca;
    sincosf(angle, &sa, &ca);
    float r0 = v.x * ca - v.y * sa;
    float r1 = v.y * ca + v.x * sa;
    u32 xp  = (u32)f2bf(v.x) | ((u32)f2bf(v.y) << 16);
    u32 rxp = (u32)f2bf(r0)  | ((u32)f2bf(r1)  << 16);
    *(u32*)&xb[(size_t)idx * 2]  = xp;
    *(u32*)&rxb[(size_t)idx * 2] = rxp;
}

// ---------- kernel 2: weight cast ----------
__global__ __launch_bounds__(256) void wcast(const float* __restrict__ a,
                                             const float* __restrict__ b,
                                             const float* __restrict__ c,
                                             const float* __restrict__ d,
                                             u16* __restrict__ out) {
    int i = blockIdx.x * 256 + threadIdx.x;        // 4M total
    int w = i >> 20, j = i & 1048575;
    float v = (w == 0) ? a[j] : (w == 1) ? b[j] : (w == 2) ? c[j] : d[j];
    out[i] = f2bf(v);
}

// ---------- kernel 3: GEMM  C = A @ W^T  (A: Mx1024 bf16, W: 1024x1024 bf16 row-major [n][k]) ----------
// MODE 0: bf16 out with (B,H,T,64) head remap (for Q/K/V)
// MODE 1: fp32 out + bias (final projection)
template <int MODE>
__global__ __launch_bounds__(256) void gemm128(const u16* __restrict__ A,
                                               const u16* __restrict__ W,
                                               u16* __restrict__ outb,
                                               float* __restrict__ outf,
                                               const float* __restrict__ bias) {
    constexpr int Kd = 1024, Nd = 1024;
    __shared__ u16 As[128 * 64];
    __shared__ u16 Bs[128 * 64];
    const int tid = threadIdx.x;
    const int m0 = blockIdx.x * 128;
    const int n0 = blockIdx.y * 128;
    const int wid = tid >> 6, lane = tid & 63;
    const int wr = wid >> 1, wc = wid & 1;      // 2x2 waves -> 64x64 each
    const int lr = lane & 15, lhi = lane >> 4;

    f32x4 acc[4][4] = {};

    for (int k0 = 0; k0 < Kd; k0 += 64) {
        if (k0) __syncthreads();
#pragma unroll
        for (int i = 0; i < 4; ++i) {
            int cidx = tid + 256 * i;
            int row = cidx >> 3, col = (cidx & 7) * 8;
            load_lds16(A + (size_t)(m0 + row) * Kd + k0 + col, &As[row * 64 + col]);
        }
#pragma unroll
        for (int i = 0; i < 4; ++i) {
            int cidx = tid + 256 * i;
            int row = cidx >> 3, col = (cidx & 7) * 8;
            load_lds16(W + (size_t)(n0 + row) * Kd + k0 + col, &Bs[row * 64 + col]);
        }
        __syncthreads();
#pragma unroll
        for (int c = 0; c < 2; ++c) {
            bf16x8 a[4], b[4];
#pragma unroll
            for (int m = 0; m < 4; ++m)
                a[m] = *(const bf16x8*)&As[(wr * 64 + m * 16 + lr) * 64 + c * 32 + lhi * 8];
#pragma unroll
            for (int n = 0; n < 4; ++n)
                b[n] = *(const bf16x8*)&Bs[(wc * 64 + n * 16 + lr) * 64 + c * 32 + lhi * 8];
#pragma unroll
            for (int m = 0; m < 4; ++m)
#pragma unroll
                for (int n = 0; n < 4; ++n)
                    acc[m][n] = __builtin_amdgcn_mfma_f32_16x16x32_bf16(a[m], b[n], acc[m][n], 0, 0, 0);
        }
    }

#pragma unroll
    for (int m = 0; m < 4; ++m) {
        int rowb = m0 + wr * 64 + m * 16 + lhi * 4;
#pragma unroll
        for (int n = 0; n < 4; ++n) {
            int col = n0 + wc * 64 + n * 16 + lr;
#pragma unroll
            for (int r = 0; r < 4; ++r) {
                int mg = rowb + r;
                float v = acc[m][n][r];
                if (MODE == 0) {
                    int bb = mg >> 11, t = mg & 2047;
                    int h = col >> 6, d = col & 63;
                    outb[((((size_t)bb * 16 + h) * 2048) + t) * 64 + d] = f2bf(v);
                } else {
                    outf[(size_t)mg * Nd + col] = v + bias[col];
                }
            }
        }
    }
}

// ---------- kernel 4: causal flash attention ----------
// Q,K,V: (B*H, T, 64) bf16.  O: (B*T, 1024) bf16 (heads merged).
__global__ __launch_bounds__(256) void attn64(const u16* __restrict__ Q,
                                              const u16* __restrict__ K,
                                              const u16* __restrict__ V,
                                              u16* __restrict__ O) {
    constexpr int T = 2048;
    __shared__ u16 Ks[64 * 64];
    __shared__ u16 Vt[64 * 64];      // transposed: Vt[d][k]
    __shared__ u16 Ps[4][16 * 64];   // per-wave P tile
    const int tid = threadIdx.x, wid = tid >> 6, lane = tid & 63;
    const int lr = lane & 15, lhi = lane >> 4;
    const int bh = blockIdx.y;
    const int q0 = blockIdx.x * 64;
    const int q0w = q0 + wid * 16;
    const size_t base = (size_t)bh * T * 64;
    const u16* Qp = Q + base;
    const u16* Kp = K + base;
    const u16* Vp = V + base;

    bf16x8 qa[2];
#pragma unroll
    for (int c = 0; c < 2; ++c)
        qa[c] = *(const bf16x8*)&Qp[(size_t)(q0w + lr) * 64 + c * 32 + lhi * 8];

    f32x4 acc[4] = {};
    float m_i[4], l_i[4];
#pragma unroll
    for (int r = 0; r < 4; ++r) { m_i[r] = -1e30f; l_i[r] = 0.f; }

    const int ntiles = (q0 >> 6) + 1;
    for (int kt = 0; kt < ntiles; ++kt) {
        const int kv0 = kt * 64;
        if (kt) __syncthreads();
        // stage K tile (linear)
#pragma unroll
        for (int i = 0; i < 2; ++i) {
            int cidx = tid + 256 * i;
            int row = cidx >> 3, col = (cidx & 7) * 8;
            load_lds16(Kp + (size_t)(kv0 + row) * 64 + col, &Ks[row * 64 + col]);
        }
        // stage V transposed
        {
            int k = tid >> 2, db = (tid & 3) * 16;
            const u16* vsrc = Vp + (size_t)(kv0 + k) * 64 + db;
            u16 tmp[16];
            *(u32x4*)&tmp[0] = *(const u32x4*)&vsrc[0];
            *(u32x4*)&tmp[8] = *(const u32x4*)&vsrc[8];
#pragma unroll
            for (int i = 0; i < 16; ++i) Vt[(db + i) * 64 + k] = tmp[i];
        }
        __syncthreads();

        if (kv0 <= q0w + 15) {
            // scores = Q @ K^T
            f32x4 s[4] = {};
#pragma unroll
            for (int c = 0; c < 2; ++c) {
#pragma unroll
                for (int n = 0; n < 4; ++n) {
                    bf16x8 kb = *(const bf16x8*)&Ks[(n * 16 + lr) * 64 + c * 32 + lhi * 8];
                    s[n] = __builtin_amdgcn_mfma_f32_16x16x32_bf16(qa[c], kb, s[n], 0, 0, 0);
                }
            }
            // mask + scale (1/sqrt(64)=0.125), row max
            float mx[4] = { -1e30f, -1e30f, -1e30f, -1e30f };
#pragma unroll
            for (int n = 0; n < 4; ++n) {
                int kvg = kv0 + n * 16 + lr;
#pragma unroll
                for (int r = 0; r < 4; ++r) {
                    int qg = q0w + lhi * 4 + r;
                    float v = (kvg <= qg) ? s[n][r] * 0.125f : -1e30f;
                    s[n][r] = v;
                    mx[r] = fmaxf(mx[r], v);
                }
            }
#pragma unroll
            for (int off = 8; off; off >>= 1)
#pragma unroll
                for (int r = 0; r < 4; ++r)
                    mx[r] = fmaxf(mx[r], __shfl_xor(mx[r], off));
            // online softmax update
            float rs[4] = { 0.f, 0.f, 0.f, 0.f };
#pragma unroll
            for (int r = 0; r < 4; ++r) {
                float mnew = fmaxf(m_i[r], mx[r]);
                float sc = __expf(m_i[r] - mnew);
                m_i[r] = mnew;
                l_i[r] *= sc;
#pragma unroll
                for (int nd = 0; nd < 4; ++nd) acc[nd][r] *= sc;
            }
#pragma unroll
            for (int n = 0; n < 4; ++n)
#pragma unroll
                for (int r = 0; r < 4; ++r) {
                    float pv = __expf(s[n][r] - m_i[r]);
                    rs[r] += pv;
                    Ps[wid][(lhi * 4 + r) * 64 + n * 16 + lr] = f2bf(pv);
                }
#pragma unroll
            for (int off = 8; off; off >>= 1)
#pragma unroll
                for (int r = 0; r < 4; ++r) rs[r] += __shfl_xor(rs[r], off);
#pragma unroll
            for (int r = 0; r < 4; ++r) l_i[r] += rs[r];
            // P @ V
            bf16x8 pa[2];
#pragma unroll
            for (int c = 0; c < 2; ++c)
                pa[c] = *(const bf16x8*)&Ps[wid][lr * 64 + c * 32 + lhi * 8];
#pragma unroll
            for (int nd = 0; nd < 4; ++nd)
#pragma unroll
                for (int c = 0; c < 2; ++c) {
                    bf16x8 vb = *(const bf16x8*)&Vt[(nd * 16 + lr) * 64 + c * 32 + lhi * 8];
                    acc[nd] = __builtin_amdgcn_mfma_f32_16x16x32_bf16(pa[c], vb, acc[nd], 0, 0, 0);
                }
        }
    }

    // epilogue: O[(b*T+q), h*64+d]
    const int b = bh >> 4, h = bh & 15;
#pragma unroll
    for (int nd = 0; nd < 4; ++nd)
#pragma unroll
        for (int r = 0; r < 4; ++r) {
            int qg = q0w + lhi * 4 + r;
            int d = h * 64 + nd * 16 + lr;
            O[(size_t)(b * 2048 + qg) * 1024 + d] = f2bf(acc[nd][r] / l_i[r]);
        }
}

// ---------- launch ----------
extern "C" void kernel_launch(void* const* d_in, const int* in_sizes, int n_in,
                              void* d_out, int out_size, void* d_ws, size_t ws_size,
                              hipStream_t stream) {
    const float* x  = (const float*)d_in[0];
    const float* Wq = (const float*)d_in[1];
    const float* Wk = (const float*)d_in[2];
    const float* Wv = (const float*)d_in[3];
    const float* Wo = (const float*)d_in[4];
    const float* bo = (const float*)d_in[5];

    char* ws = (char*)d_ws;
    u16* Wqb = (u16*)ws;                        // 1M elems
    u16* Wkb = Wqb + (1 << 20);
    u16* Wvb = Wkb + (1 << 20);
    u16* Wob = Wvb + (1 << 20);
    u16* xb  = (u16*)(ws + (size_t)8 * 1024 * 1024);
    u16* rxb = xb  + (size_t)8388608;
    u16* Qb  = rxb + (size_t)8388608;
    u16* Kb  = Qb  + (size_t)8388608;
    u16* Vb  = Kb  + (size_t)8388608;
    u16* Ob  = Vb  + (size_t)8388608;

    rope_cast<<<16384, 256, 0, stream>>>(x, xb, rxb);
    wcast<<<16384, 256, 0, stream>>>(Wq, Wk, Wv, Wo, Wqb);

    dim3 g(64, 8);
    gemm128<0><<<g, 256, 0, stream>>>(rxb, Wqb, Qb, nullptr, nullptr);
    gemm128<0><<<g, 256, 0, stream>>>(rxb, Wkb, Kb, nullptr, nullptr);
    gemm128<0><<<g, 256, 0, stream>>>(xb,  Wvb, Vb, nullptr, nullptr);

    attn64<<<dim3(32, 64), 256, 0, stream>>>(Qb, Kb, Vb, Ob);

    gemm128<1><<<g, 256, 0, stream>>>(Ob, Wob, nullptr, (float*)d_out, bo);
}

// Round 6
// 493.621 us; speedup vs baseline: 1.0904x; 1.0904x over previous
//
#include <hip/hip_runtime.h>

// ---------- types ----------
typedef unsigned short u16;
typedef unsigned int   u32;
typedef __attribute__((ext_vector_type(4))) float f32x4;
typedef __attribute__((ext_vector_type(8))) __bf16 bf16x8;
typedef __attribute__((ext_vector_type(2))) u32  u32x2;
typedef __attribute__((ext_vector_type(4))) u32  u32x4;

#define LDS_CAST(p) ((__attribute__((address_space(3))) void*)(p))
#define GLB_CAST(p) ((const __attribute__((address_space(1))) void*)(p))

__device__ __forceinline__ void load_lds16(const void* g, void* l) {
    __builtin_amdgcn_global_load_lds(GLB_CAST(g), LDS_CAST(l), 16, 0, 0);
}

__device__ __forceinline__ u32 lds_off(const void* p) {
    return (u32)(size_t)(const __attribute__((address_space(3))) void*)p;
}

__device__ __forceinline__ u16 f2bf(float f) {
    union { float f; u32 u; } v; v.f = f;
    u32 r = (v.u + 0x7FFFu + ((v.u >> 16) & 1u)) >> 16;
    return (u16)r;
}

// ---------- constants ----------
// B=4, T=2048, E=1024, H=16, hd=64, M = B*T = 8192
// ws layout (bytes):
//  [0,8MB)    : Wq,Wk,Wv,Wo bf16 (2MB each)
//  [8,24MB)   : x bf16
//  [24,40MB)  : rx bf16
//  [40,56MB)  : Q (B,H,T,64) bf16
//  [56,72MB)  : K
//  [72,88MB)  : V
//  [88,104MB) : O (B*T, 1024) bf16

// ---------- kernel 1: RoPE + cast ----------
__global__ __launch_bounds__(256) void rope_cast(const float* __restrict__ x,
                                                 u16* __restrict__ xb,
                                                 u16* __restrict__ rxb) {
    int idx = blockIdx.x * 256 + threadIdx.x;      // one pair, total 4194304
    int e2 = (idx & 511) * 2;
    int t  = (idx >> 9) & 2047;
    float2 v = *(const float2*)&x[(size_t)idx * 2];
    float theta = expf(-0.0089944730194981f * (float)e2);
    float angle = (float)t * theta;
    float sa, ca;
    sincosf(angle, &sa, &ca);
    float r0 = v.x * ca - v.y * sa;
    float r1 = v.y * ca + v.x * sa;
    u32 xp  = (u32)f2bf(v.x) | ((u32)f2bf(v.y) << 16);
    u32 rxp = (u32)f2bf(r0)  | ((u32)f2bf(r1)  << 16);
    *(u32*)&xb[(size_t)idx * 2]  = xp;
    *(u32*)&rxb[(size_t)idx * 2] = rxp;
}

// ---------- kernel 2: weight cast ----------
__global__ __launch_bounds__(256) void wcast(const float* __restrict__ a,
                                             const float* __restrict__ b,
                                             const float* __restrict__ c,
                                             const float* __restrict__ d,
                                             u16* __restrict__ out) {
    int i = blockIdx.x * 256 + threadIdx.x;        // 4M total
    int w = i >> 20, j = i & 1048575;
    float v = (w == 0) ? a[j] : (w == 1) ? b[j] : (w == 2) ? c[j] : d[j];
    out[i] = f2bf(v);
}

// ---------- kernel 3: GEMM  C = A @ W^T ----------
template <int MODE>
__global__ __launch_bounds__(256) void gemm128(const u16* __restrict__ A,
                                               const u16* __restrict__ W,
                                               u16* __restrict__ outb,
                                               float* __restrict__ outf,
                                               const float* __restrict__ bias) {
    constexpr int Kd = 1024, Nd = 1024;
    __shared__ u16 As[128 * 64];
    __shared__ u16 Bs[128 * 64];
    const int tid = threadIdx.x;
    const int m0 = blockIdx.x * 128;
    const int n0 = blockIdx.y * 128;
    const int wid = tid >> 6, lane = tid & 63;
    const int wr = wid >> 1, wc = wid & 1;
    const int lr = lane & 15, lhi = lane >> 4;

    f32x4 acc[4][4] = {};

    for (int k0 = 0; k0 < Kd; k0 += 64) {
        if (k0) __syncthreads();
#pragma unroll
        for (int i = 0; i < 4; ++i) {
            int cidx = tid + 256 * i;
            int row = cidx >> 3, col = (cidx & 7) * 8;
            load_lds16(A + (size_t)(m0 + row) * Kd + k0 + col, &As[row * 64 + col]);
        }
#pragma unroll
        for (int i = 0; i < 4; ++i) {
            int cidx = tid + 256 * i;
            int row = cidx >> 3, col = (cidx & 7) * 8;
            load_lds16(W + (size_t)(n0 + row) * Kd + k0 + col, &Bs[row * 64 + col]);
        }
        __syncthreads();
#pragma unroll
        for (int c = 0; c < 2; ++c) {
            bf16x8 a[4], b[4];
#pragma unroll
            for (int m = 0; m < 4; ++m)
                a[m] = *(const bf16x8*)&As[(wr * 64 + m * 16 + lr) * 64 + c * 32 + lhi * 8];
#pragma unroll
            for (int n = 0; n < 4; ++n)
                b[n] = *(const bf16x8*)&Bs[(wc * 64 + n * 16 + lr) * 64 + c * 32 + lhi * 8];
#pragma unroll
            for (int m = 0; m < 4; ++m)
#pragma unroll
                for (int n = 0; n < 4; ++n)
                    acc[m][n] = __builtin_amdgcn_mfma_f32_16x16x32_bf16(a[m], b[n], acc[m][n], 0, 0, 0);
        }
    }

#pragma unroll
    for (int m = 0; m < 4; ++m) {
        int rowb = m0 + wr * 64 + m * 16 + lhi * 4;
#pragma unroll
        for (int n = 0; n < 4; ++n) {
            int col = n0 + wc * 64 + n * 16 + lr;
#pragma unroll
            for (int r = 0; r < 4; ++r) {
                int mg = rowb + r;
                float v = acc[m][n][r];
                if (MODE == 0) {
                    int bb = mg >> 11, t = mg & 2047;
                    int h = col >> 6, d = col & 63;
                    outb[((((size_t)bb * 16 + h) * 2048) + t) * 64 + d] = f2bf(v);
                } else {
                    outf[(size_t)mg * Nd + col] = v + bias[col];
                }
            }
        }
    }
}

// ---------- kernel 4: causal flash attention (v2.1) ----------
// Q,K,V: (B*H, T, 64) bf16.  O: (B*T, 1024) bf16.
// K LDS: row-major 64x64, XOR-swizzled (byte ^= (row&7)<<4) via pre-swizzled
//        global source (rule 21) + swizzled ds_read_b128 -> ~2-way.
// V LDS: subtiled [k/4][d/16][4][16]; V[k][d] at u16 idx
//        (k>>2)*256 + (d>>4)*64 + (k&3)*16 + (d&15).
//        PV B-frags via ds_read_b64_tr_b16 pairs (model: per-lane strided
//        read, 4 bf16 at addr + j*32B), with one-time in-kernel self-check
//        selecting a scalar-read fallback if the model is wrong.
// P LDS: per-wave 16x64, same XOR swizzle on write+read.
// Double-buffered K/V, stage-next-before-compute, 1 barrier/tile.
__global__ __launch_bounds__(256) void attn64(const u16* __restrict__ Q,
                                              const u16* __restrict__ K,
                                              const u16* __restrict__ V,
                                              u16* __restrict__ O) {
    constexpr int T = 2048;
    __shared__ u16 Ks[2][64 * 64];
    __shared__ u16 Vs[2][64 * 64];
    __shared__ u16 Ps[4][16 * 64];
    const int tid = threadIdx.x, wid = tid >> 6, lane = tid & 63;
    const int lr = lane & 15, lhi = lane >> 4;
    const int bh = blockIdx.y;
    const int qt = 31 - blockIdx.x;               // heavy blocks dispatch first
    const int q0 = qt * 64;
    const int q0w = q0 + wid * 16;
    const size_t base = (size_t)bh * T * 64;
    const u16* Qp = Q + base;
    const u16* Kp = K + base;
    const u16* Vp = V + base;

    // Q fragments, pre-scaled by 1/sqrt(64)=0.125 (exact in bf16)
    bf16x8 qa[2];
#pragma unroll
    for (int c = 0; c < 2; ++c) {
        bf16x8 t = *(const bf16x8*)&Qp[(size_t)(q0w + lr) * 64 + c * 32 + lhi * 8];
        bf16x8 o;
#pragma unroll
        for (int i = 0; i < 8; ++i) o[i] = (__bf16)((float)t[i] * 0.125f);
        qa[c] = o;
    }

    f32x4 acc[4] = {};
    float m_i[4], l_i[4];
#pragma unroll
    for (int r = 0; r < 4; ++r) { m_i[r] = -1e30f; l_i[r] = 0.f; }

    const int nt = qt + 1;

    // ---- one-time tr_read self-check: fill Vs[0] with value=index ----
    {
        u16* vt = (u16*)&Vs[0][0];
#pragma unroll
        for (int j = 0; j < 16; ++j) vt[tid * 16 + j] = (u16)(tid * 16 + j);
    }
    __syncthreads();
    bool use_tr;
    {
        const u32 vsb0 = lds_off(&Vs[0][0]);
        bool ok = true;
#pragma unroll
        for (int t = 0; t < 2; ++t) {
            const int c = t ? 1 : 0, nd = t ? 3 : 0;
            u32 a = vsb0 + (u32)((c * 32 + lhi * 8 + nd) * 128 + lr * 2);
            u32x2 lo, hi;
            asm volatile("ds_read_b64_tr_b16 %0, %2\n\t"
                         "ds_read_b64_tr_b16 %1, %2 offset:512"
                         : "=&v"(lo), "=&v"(hi) : "v"(a));
            asm volatile("s_waitcnt lgkmcnt(0)" ::: "memory");
            __builtin_amdgcn_sched_barrier(0);
            union { u32 w[4]; u16 h[8]; } u;
            u.w[0] = lo.x; u.w[1] = lo.y; u.w[2] = hi.x; u.w[3] = hi.y;
#pragma unroll
            for (int i = 0; i < 8; ++i) {
                int k = c * 32 + lhi * 8 + i;
                int e = ((k >> 2) << 8) + (nd << 6) + ((k & 3) << 4) + lr;
                ok = ok && (u.h[i] == (u16)e);
            }
        }
        use_tr = (bool)__all((int)ok);
    }
    __syncthreads();

    // ---- stage helper (macro to keep gload_lds literal sizes) ----
#define STAGE(bb, kv0s)                                                          \
    {                                                                            \
        _Pragma("unroll")                                                        \
        for (int i = 0; i < 2; ++i) {                                            \
            int q = tid + 256 * i;                                               \
            int krow = q >> 3;                                                   \
            int kcol = ((q & 7) ^ (krow & 7)) * 8;                               \
            load_lds16(Kp + (size_t)((kv0s) + krow) * 64 + kcol, &Ks[bb][q * 8]);\
            int vk = ((q >> 5) << 2) + ((q >> 1) & 3);                           \
            int vd = (((q >> 3) & 3) << 4) + ((q & 1) << 3);                     \
            load_lds16(Vp + (size_t)((kv0s) + vk) * 64 + vd, &Vs[bb][q * 8]);    \
        }                                                                        \
    }

    STAGE(0, 0);
    __syncthreads();

    int buf = 0;
    for (int kt = 0; kt < nt; ++kt) {
        const int kv0 = kt * 64;
        if (kt + 1 < nt) STAGE(buf ^ 1, kv0 + 64);

        // ---- QK^T ----
        const u16* ks = Ks[buf];
        f32x4 s4[4] = {};
        __builtin_amdgcn_s_setprio(1);
#pragma unroll
        for (int c = 0; c < 2; ++c)
#pragma unroll
            for (int n = 0; n < 4; ++n) {
                int r = n * 16 + lr;
                bf16x8 kb = *(const bf16x8*)&ks[r * 64 + ((c * 32 + lhi * 8) ^ ((r & 7) * 8))];
                s4[n] = __builtin_amdgcn_mfma_f32_16x16x32_bf16(qa[c], kb, s4[n], 0, 0, 0);
            }
        __builtin_amdgcn_s_setprio(0);

        // ---- mask (diagonal tile only) ----
        if (kt == nt - 1) {
#pragma unroll
            for (int n = 0; n < 4; ++n) {
                int kvg = kv0 + n * 16 + lr;
#pragma unroll
                for (int r = 0; r < 4; ++r)
                    if (kvg > q0w + lhi * 4 + r) s4[n][r] = -1e30f;
            }
        }

        // ---- online softmax ----
        float mx[4] = { -1e30f, -1e30f, -1e30f, -1e30f };
#pragma unroll
        for (int n = 0; n < 4; ++n)
#pragma unroll
            for (int r = 0; r < 4; ++r) mx[r] = fmaxf(mx[r], s4[n][r]);
#pragma unroll
        for (int off = 8; off; off >>= 1)
#pragma unroll
            for (int r = 0; r < 4; ++r) mx[r] = fmaxf(mx[r], __shfl_xor(mx[r], off));

        float rs[4] = { 0.f, 0.f, 0.f, 0.f };
#pragma unroll
        for (int r = 0; r < 4; ++r) {
            float mnew = fmaxf(m_i[r], mx[r]);
            float sc = __expf(m_i[r] - mnew);
            m_i[r] = mnew;
            l_i[r] *= sc;
#pragma unroll
            for (int nd = 0; nd < 4; ++nd) acc[nd][r] *= sc;
        }
        u16* pw = Ps[wid];
#pragma unroll
        for (int n = 0; n < 4; ++n)
#pragma unroll
            for (int r = 0; r < 4; ++r) {
                float pv = __expf(s4[n][r] - m_i[r]);
                rs[r] += pv;
                int qloc = lhi * 4 + r;
                pw[qloc * 64 + ((n * 16 + lr) ^ ((qloc & 7) * 8))] = f2bf(pv);
            }
#pragma unroll
        for (int off = 8; off; off >>= 1)
#pragma unroll
            for (int r = 0; r < 4; ++r) rs[r] += __shfl_xor(rs[r], off);
#pragma unroll
        for (int r = 0; r < 4; ++r) l_i[r] += rs[r];

        // ---- P @ V ----
        const u16* vcur = Vs[buf];
        const u32 vsb = lds_off(&Vs[buf][0]);
        __builtin_amdgcn_s_setprio(1);
#pragma unroll
        for (int c = 0; c < 2; ++c) {
            bf16x8 pa = *(const bf16x8*)&pw[lr * 64 + ((c * 32 + lhi * 8) ^ ((lr & 7) * 8))];
            union { bf16x8 v; u32 w[4]; u16 h[8]; } vb[4];
            if (use_tr) {
                u32x2 lo[4], hi[4];
#pragma unroll
                for (int nd = 0; nd < 4; ++nd) {
                    u32 a = vsb + (u32)((c * 32 + lhi * 8 + nd) * 128 + lr * 2);
                    asm volatile("ds_read_b64_tr_b16 %0, %2\n\t"
                                 "ds_read_b64_tr_b16 %1, %2 offset:512"
                                 : "=&v"(lo[nd]), "=&v"(hi[nd]) : "v"(a));
                }
                asm volatile("s_waitcnt lgkmcnt(0)" ::: "memory");
                __builtin_amdgcn_sched_barrier(0);
#pragma unroll
                for (int nd = 0; nd < 4; ++nd) {
                    vb[nd].w[0] = lo[nd].x; vb[nd].w[1] = lo[nd].y;
                    vb[nd].w[2] = hi[nd].x; vb[nd].w[3] = hi[nd].y;
                }
            } else {
#pragma unroll
                for (int nd = 0; nd < 4; ++nd)
#pragma unroll
                    for (int i = 0; i < 8; ++i) {
                        int k = c * 32 + lhi * 8 + i;
                        vb[nd].h[i] = vcur[((k >> 2) << 8) + (nd << 6) + ((k & 3) << 4) + lr];
                    }
            }
#pragma unroll
            for (int nd = 0; nd < 4; ++nd)
                acc[nd] = __builtin_amdgcn_mfma_f32_16x16x32_bf16(pa, vb[nd].v, acc[nd], 0, 0, 0);
        }
        __builtin_amdgcn_s_setprio(0);

        __syncthreads();
        buf ^= 1;
    }
#undef STAGE

    // ---- epilogue ----
    const int b = bh >> 4, h = bh & 15;
#pragma unroll
    for (int nd = 0; nd < 4; ++nd)
#pragma unroll
        for (int r = 0; r < 4; ++r) {
            int qg = q0w + lhi * 4 + r;
            int d = h * 64 + nd * 16 + lr;
            O[(size_t)(b * 2048 + qg) * 1024 + d] = f2bf(acc[nd][r] / l_i[r]);
        }
}

// ---------- launch ----------
extern "C" void kernel_launch(void* const* d_in, const int* in_sizes, int n_in,
                              void* d_out, int out_size, void* d_ws, size_t ws_size,
                              hipStream_t stream) {
    const float* x  = (const float*)d_in[0];
    const float* Wq = (const float*)d_in[1];
    const float* Wk = (const float*)d_in[2];
    const float* Wv = (const float*)d_in[3];
    const float* Wo = (const float*)d_in[4];
    const float* bo = (const float*)d_in[5];

    char* ws = (char*)d_ws;
    u16* Wqb = (u16*)ws;
    u16* Wkb = Wqb + (1 << 20);
    u16* Wvb = Wkb + (1 << 20);
    u16* Wob = Wvb + (1 << 20);
    u16* xb  = (u16*)(ws + (size_t)8 * 1024 * 1024);
    u16* rxb = xb  + (size_t)8388608;
    u16* Qb  = rxb + (size_t)8388608;
    u16* Kb  = Qb  + (size_t)8388608;
    u16* Vb  = Kb  + (size_t)8388608;
    u16* Ob  = Vb  + (size_t)8388608;

    rope_cast<<<16384, 256, 0, stream>>>(x, xb, rxb);
    wcast<<<16384, 256, 0, stream>>>(Wq, Wk, Wv, Wo, Wqb);

    dim3 g(64, 8);
    gemm128<0><<<g, 256, 0, stream>>>(rxb, Wqb, Qb, nullptr, nullptr);
    gemm128<0><<<g, 256, 0, stream>>>(rxb, Wkb, Kb, nullptr, nullptr);
    gemm128<0><<<g, 256, 0, stream>>>(xb,  Wvb, Vb, nullptr, nullptr);

    attn64<<<dim3(32, 64), 256, 0, stream>>>(Qb, Kb, Vb, Ob);

    gemm128<1><<<g, 256, 0, stream>>>(Ob, Wob, nullptr, (float*)d_out, bo);
}

// Round 7
// 386.231 us; speedup vs baseline: 1.3936x; 1.2780x over previous
//
#include <hip/hip_runtime.h>

// ---------- types ----------
typedef unsigned short u16;
typedef unsigned int   u32;
typedef __attribute__((ext_vector_type(4))) float f32x4;
typedef __attribute__((ext_vector_type(8))) __bf16 bf16x8;
typedef __attribute__((ext_vector_type(2))) u32  u32x2;
typedef __attribute__((ext_vector_type(4))) u32  u32x4;

#define LDS_CAST(p) ((__attribute__((address_space(3))) void*)(p))
#define GLB_CAST(p) ((const __attribute__((address_space(1))) void*)(p))

__device__ __forceinline__ void load_lds16(const void* g, void* l) {
    __builtin_amdgcn_global_load_lds(GLB_CAST(g), LDS_CAST(l), 16, 0, 0);
}

__device__ __forceinline__ u32 lds_off(const void* p) {
    return (u32)(size_t)(const __attribute__((address_space(3))) void*)p;
}

__device__ __forceinline__ u16 f2bf(float f) {
    union { float f; u32 u; } v; v.f = f;
    u32 r = (v.u + 0x7FFFu + ((v.u >> 16) & 1u)) >> 16;
    return (u16)r;
}

// ---------- kernel 1: RoPE + cast ----------
__global__ __launch_bounds__(256) void rope_cast(const float* __restrict__ x,
                                                 u16* __restrict__ xb,
                                                 u16* __restrict__ rxb) {
    int idx = blockIdx.x * 256 + threadIdx.x;      // one pair, total 4194304
    int e2 = (idx & 511) * 2;
    int t  = (idx >> 9) & 2047;
    float2 v = *(const float2*)&x[(size_t)idx * 2];
    float theta = expf(-0.0089944730194981f * (float)e2);
    float angle = (float)t * theta;
    float sa, ca;
    sincosf(angle, &sa, &ca);
    float r0 = v.x * ca - v.y * sa;
    float r1 = v.y * ca + v.x * sa;
    u32 xp  = (u32)f2bf(v.x) | ((u32)f2bf(v.y) << 16);
    u32 rxp = (u32)f2bf(r0)  | ((u32)f2bf(r1)  << 16);
    *(u32*)&xb[(size_t)idx * 2]  = xp;
    *(u32*)&rxb[(size_t)idx * 2] = rxp;
}

// ---------- kernel 2: weight cast ----------
__global__ __launch_bounds__(256) void wcast(const float* __restrict__ a,
                                             const float* __restrict__ b,
                                             const float* __restrict__ c,
                                             const float* __restrict__ d,
                                             u16* __restrict__ out) {
    int i = blockIdx.x * 256 + threadIdx.x;        // 4M total
    int w = i >> 20, j = i & 1048575;
    float v = (w == 0) ? a[j] : (w == 1) ? b[j] : (w == 2) ? c[j] : d[j];
    out[i] = f2bf(v);
}

// ---------- kernel 3: GEMM  C = A @ W^T ----------
template <int MODE>
__global__ __launch_bounds__(256) void gemm128(const u16* __restrict__ A,
                                               const u16* __restrict__ W,
                                               u16* __restrict__ outb,
                                               float* __restrict__ outf,
                                               const float* __restrict__ bias) {
    constexpr int Kd = 1024, Nd = 1024;
    __shared__ u16 As[128 * 64];
    __shared__ u16 Bs[128 * 64];
    const int tid = threadIdx.x;
    const int m0 = blockIdx.x * 128;
    const int n0 = blockIdx.y * 128;
    const int wid = tid >> 6, lane = tid & 63;
    const int wr = wid >> 1, wc = wid & 1;
    const int lr = lane & 15, lhi = lane >> 4;

    f32x4 acc[4][4] = {};

    for (int k0 = 0; k0 < Kd; k0 += 64) {
        if (k0) __syncthreads();
#pragma unroll
        for (int i = 0; i < 4; ++i) {
            int cidx = tid + 256 * i;
            int row = cidx >> 3, col = (cidx & 7) * 8;
            load_lds16(A + (size_t)(m0 + row) * Kd + k0 + col, &As[row * 64 + col]);
        }
#pragma unroll
        for (int i = 0; i < 4; ++i) {
            int cidx = tid + 256 * i;
            int row = cidx >> 3, col = (cidx & 7) * 8;
            load_lds16(W + (size_t)(n0 + row) * Kd + k0 + col, &Bs[row * 64 + col]);
        }
        __syncthreads();
#pragma unroll
        for (int c = 0; c < 2; ++c) {
            bf16x8 a[4], b[4];
#pragma unroll
            for (int m = 0; m < 4; ++m)
                a[m] = *(const bf16x8*)&As[(wr * 64 + m * 16 + lr) * 64 + c * 32 + lhi * 8];
#pragma unroll
            for (int n = 0; n < 4; ++n)
                b[n] = *(const bf16x8*)&Bs[(wc * 64 + n * 16 + lr) * 64 + c * 32 + lhi * 8];
#pragma unroll
            for (int m = 0; m < 4; ++m)
#pragma unroll
                for (int n = 0; n < 4; ++n)
                    acc[m][n] = __builtin_amdgcn_mfma_f32_16x16x32_bf16(a[m], b[n], acc[m][n], 0, 0, 0);
        }
    }

#pragma unroll
    for (int m = 0; m < 4; ++m) {
        int rowb = m0 + wr * 64 + m * 16 + lhi * 4;
#pragma unroll
        for (int n = 0; n < 4; ++n) {
            int col = n0 + wc * 64 + n * 16 + lr;
#pragma unroll
            for (int r = 0; r < 4; ++r) {
                int mg = rowb + r;
                float v = acc[m][n][r];
                if (MODE == 0) {
                    int bb = mg >> 11, t = mg & 2047;
                    int h = col >> 6, d = col & 63;
                    outb[((((size_t)bb * 16 + h) * 2048) + t) * 64 + d] = f2bf(v);
                } else {
                    outf[(size_t)mg * Nd + col] = v + bias[col];
                }
            }
        }
    }
}

// ---------- attention per-tile pass (one 16-row q-tile vs one 64-kv tile) ----------
__device__ __forceinline__ void attn_pass(const bf16x8 (&qa)[2], f32x4 (&acc)[4],
                                          float (&m_i)[4], float (&l_i)[4],
                                          const u16* ks, const u16* vcur, u32 vsb,
                                          u16* pw, int lr, int lhi,
                                          int kv0, int q0w, bool diag, bool use_tr) {
    // ---- QK^T ----
    f32x4 s4[4] = {};
    __builtin_amdgcn_s_setprio(1);
#pragma unroll
    for (int c = 0; c < 2; ++c)
#pragma unroll
        for (int n = 0; n < 4; ++n) {
            int r = n * 16 + lr;
            bf16x8 kb = *(const bf16x8*)&ks[r * 64 + ((c * 32 + lhi * 8) ^ ((r & 7) * 8))];
            s4[n] = __builtin_amdgcn_mfma_f32_16x16x32_bf16(qa[c], kb, s4[n], 0, 0, 0);
        }
    __builtin_amdgcn_s_setprio(0);

    // ---- mask (diagonal tile only) ----
    if (diag) {
#pragma unroll
        for (int n = 0; n < 4; ++n) {
            int kvg = kv0 + n * 16 + lr;
#pragma unroll
            for (int r = 0; r < 4; ++r)
                if (kvg > q0w + lhi * 4 + r) s4[n][r] = -1e30f;
        }
    }

    // ---- online softmax ----
    float mx[4] = { -1e30f, -1e30f, -1e30f, -1e30f };
#pragma unroll
    for (int n = 0; n < 4; ++n)
#pragma unroll
        for (int r = 0; r < 4; ++r) mx[r] = fmaxf(mx[r], s4[n][r]);
#pragma unroll
    for (int off = 8; off; off >>= 1)
#pragma unroll
        for (int r = 0; r < 4; ++r) mx[r] = fmaxf(mx[r], __shfl_xor(mx[r], off));

    float rs[4] = { 0.f, 0.f, 0.f, 0.f };
#pragma unroll
    for (int r = 0; r < 4; ++r) {
        float mnew = fmaxf(m_i[r], mx[r]);
        float sc = __expf(m_i[r] - mnew);
        m_i[r] = mnew;
        l_i[r] *= sc;
#pragma unroll
        for (int nd = 0; nd < 4; ++nd) acc[nd][r] *= sc;
    }
#pragma unroll
    for (int n = 0; n < 4; ++n)
#pragma unroll
        for (int r = 0; r < 4; ++r) {
            float pv = __expf(s4[n][r] - m_i[r]);
            rs[r] += pv;
            int qloc = lhi * 4 + r;
            pw[qloc * 64 + ((n * 16 + lr) ^ ((qloc & 7) * 8))] = f2bf(pv);
        }
#pragma unroll
    for (int off = 8; off; off >>= 1)
#pragma unroll
        for (int r = 0; r < 4; ++r) rs[r] += __shfl_xor(rs[r], off);
#pragma unroll
    for (int r = 0; r < 4; ++r) l_i[r] += rs[r];

    // ---- P @ V ----
    __builtin_amdgcn_s_setprio(1);
#pragma unroll
    for (int c = 0; c < 2; ++c) {
        bf16x8 pa = *(const bf16x8*)&pw[lr * 64 + ((c * 32 + lhi * 8) ^ ((lr & 7) * 8))];
        union { bf16x8 v; u32 w[4]; u16 h[8]; } vb[4];
        if (use_tr) {
            u32x2 lo[4], hi[4];
#pragma unroll
            for (int nd = 0; nd < 4; ++nd) {
                u32 a = vsb + (u32)((c * 32 + lhi * 8 + nd) * 128 + lr * 2);
                asm volatile("ds_read_b64_tr_b16 %0, %2\n\t"
                             "ds_read_b64_tr_b16 %1, %2 offset:512"
                             : "=&v"(lo[nd]), "=&v"(hi[nd]) : "v"(a));
            }
            asm volatile("s_waitcnt lgkmcnt(0)" ::: "memory");
            __builtin_amdgcn_sched_barrier(0);
#pragma unroll
            for (int nd = 0; nd < 4; ++nd) {
                vb[nd].w[0] = lo[nd].x; vb[nd].w[1] = lo[nd].y;
                vb[nd].w[2] = hi[nd].x; vb[nd].w[3] = hi[nd].y;
            }
        } else {
#pragma unroll
            for (int nd = 0; nd < 4; ++nd)
#pragma unroll
                for (int i = 0; i < 8; ++i) {
                    int k = c * 32 + lhi * 8 + i;
                    vb[nd].h[i] = vcur[((k >> 2) << 8) + (nd << 6) + ((k & 3) << 4) + lr];
                }
        }
#pragma unroll
        for (int nd = 0; nd < 4; ++nd)
            acc[nd] = __builtin_amdgcn_mfma_f32_16x16x32_bf16(pa, vb[nd].v, acc[nd], 0, 0, 0);
    }
    __builtin_amdgcn_s_setprio(0);
}

// ---------- kernel 4: causal flash attention (v3 — diagonal-paired) ----------
// Each block handles q-tiles qtA = bx and qtB = 31-bx: total compute passes
// per block = (qtA+1)+(qtB+1) = 33 -> perfect load balance.
// Grid 16x64 = 1024 blocks = exactly 4 blocks/CU (LDS limit) -> fully resident.
// KV tiles 0..qtA staged once, used by both passes.
__global__ __launch_bounds__(256) void attn64(const u16* __restrict__ Q,
                                              const u16* __restrict__ K,
                                              const u16* __restrict__ V,
                                              u16* __restrict__ O) {
    constexpr int T = 2048;
    __shared__ u16 Ks[2][64 * 64];
    __shared__ u16 Vs[2][64 * 64];
    __shared__ u16 Ps[4][16 * 64];
    const int tid = threadIdx.x, wid = tid >> 6, lane = tid & 63;
    const int lr = lane & 15, lhi = lane >> 4;
    const int bh = blockIdx.y;
    const int qtA = blockIdx.x;            // 0..15
    const int qtB = 31 - qtA;              // 16..31
    const int q0wA = qtA * 64 + wid * 16;
    const int q0wB = qtB * 64 + wid * 16;
    const size_t base = (size_t)bh * T * 64;
    const u16* Qp = Q + base;
    const u16* Kp = K + base;
    const u16* Vp = V + base;

    // Q fragments for both tiles, pre-scaled by 1/sqrt(64)=0.125
    bf16x8 qaA[2], qaB[2];
#pragma unroll
    for (int c = 0; c < 2; ++c) {
        bf16x8 tA = *(const bf16x8*)&Qp[(size_t)(q0wA + lr) * 64 + c * 32 + lhi * 8];
        bf16x8 tB = *(const bf16x8*)&Qp[(size_t)(q0wB + lr) * 64 + c * 32 + lhi * 8];
        bf16x8 oA, oB;
#pragma unroll
        for (int i = 0; i < 8; ++i) {
            oA[i] = (__bf16)((float)tA[i] * 0.125f);
            oB[i] = (__bf16)((float)tB[i] * 0.125f);
        }
        qaA[c] = oA; qaB[c] = oB;
    }

    f32x4 accA[4] = {}, accB[4] = {};
    float m_iA[4], l_iA[4], m_iB[4], l_iB[4];
#pragma unroll
    for (int r = 0; r < 4; ++r) {
        m_iA[r] = -1e30f; l_iA[r] = 0.f;
        m_iB[r] = -1e30f; l_iB[r] = 0.f;
    }

    // ---- one-time tr_read self-check: fill Vs[0] with value=index ----
    {
        u16* vt = (u16*)&Vs[0][0];
#pragma unroll
        for (int j = 0; j < 16; ++j) vt[tid * 16 + j] = (u16)(tid * 16 + j);
    }
    __syncthreads();
    bool use_tr;
    {
        const u32 vsb0 = lds_off(&Vs[0][0]);
        bool ok = true;
#pragma unroll
        for (int t = 0; t < 2; ++t) {
            const int c = t ? 1 : 0, nd = t ? 3 : 0;
            u32 a = vsb0 + (u32)((c * 32 + lhi * 8 + nd) * 128 + lr * 2);
            u32x2 lo, hi;
            asm volatile("ds_read_b64_tr_b16 %0, %2\n\t"
                         "ds_read_b64_tr_b16 %1, %2 offset:512"
                         : "=&v"(lo), "=&v"(hi) : "v"(a));
            asm volatile("s_waitcnt lgkmcnt(0)" ::: "memory");
            __builtin_amdgcn_sched_barrier(0);
            union { u32 w[4]; u16 h[8]; } u;
            u.w[0] = lo.x; u.w[1] = lo.y; u.w[2] = hi.x; u.w[3] = hi.y;
#pragma unroll
            for (int i = 0; i < 8; ++i) {
                int k = c * 32 + lhi * 8 + i;
                int e = ((k >> 2) << 8) + (nd << 6) + ((k & 3) << 4) + lr;
                ok = ok && (u.h[i] == (u16)e);
            }
        }
        use_tr = (bool)__all((int)ok);
    }
    __syncthreads();

    // ---- stage helper ----
#define STAGE(bb, kv0s)                                                          \
    {                                                                            \
        _Pragma("unroll")                                                        \
        for (int i = 0; i < 2; ++i) {                                            \
            int q = tid + 256 * i;                                               \
            int krow = q >> 3;                                                   \
            int kcol = ((q & 7) ^ (krow & 7)) * 8;                               \
            load_lds16(Kp + (size_t)((kv0s) + krow) * 64 + kcol, &Ks[bb][q * 8]);\
            int vk = ((q >> 5) << 2) + ((q >> 1) & 3);                           \
            int vd = (((q >> 3) & 3) << 4) + ((q & 1) << 3);                     \
            load_lds16(Vp + (size_t)((kv0s) + vk) * 64 + vd, &Vs[bb][q * 8]);    \
        }                                                                        \
    }

    STAGE(0, 0);
    __syncthreads();

    u16* pw = Ps[wid];
    int buf = 0;
    for (int kt = 0; kt <= qtB; ++kt) {
        const int kv0 = kt * 64;
        if (kt < qtB) STAGE(buf ^ 1, kv0 + 64);

        const u16* ks = Ks[buf];
        const u16* vcur = Vs[buf];
        const u32 vsb = lds_off(vcur);

        if (kt <= qtA)
            attn_pass(qaA, accA, m_iA, l_iA, ks, vcur, vsb, pw, lr, lhi,
                      kv0, q0wA, kt == qtA, use_tr);
        attn_pass(qaB, accB, m_iB, l_iB, ks, vcur, vsb, pw, lr, lhi,
                  kv0, q0wB, kt == qtB, use_tr);

        __syncthreads();
        buf ^= 1;
    }
#undef STAGE

    // ---- epilogue: O[(b*T+q), h*64+d] for both tiles ----
    const int b = bh >> 4, h = bh & 15;
#pragma unroll
    for (int nd = 0; nd < 4; ++nd)
#pragma unroll
        for (int r = 0; r < 4; ++r) {
            int d = h * 64 + nd * 16 + lr;
            int qgA = q0wA + lhi * 4 + r;
            int qgB = q0wB + lhi * 4 + r;
            O[(size_t)(b * 2048 + qgA) * 1024 + d] = f2bf(accA[nd][r] / l_iA[r]);
            O[(size_t)(b * 2048 + qgB) * 1024 + d] = f2bf(accB[nd][r] / l_iB[r]);
        }
}

// ---------- launch ----------
extern "C" void kernel_launch(void* const* d_in, const int* in_sizes, int n_in,
                              void* d_out, int out_size, void* d_ws, size_t ws_size,
                              hipStream_t stream) {
    const float* x  = (const float*)d_in[0];
    const float* Wq = (const float*)d_in[1];
    const float* Wk = (const float*)d_in[2];
    const float* Wv = (const float*)d_in[3];
    const float* Wo = (const float*)d_in[4];
    const float* bo = (const float*)d_in[5];

    char* ws = (char*)d_ws;
    u16* Wqb = (u16*)ws;
    u16* Wkb = Wqb + (1 << 20);
    u16* Wvb = Wkb + (1 << 20);
    u16* Wob = Wvb + (1 << 20);
    u16* xb  = (u16*)(ws + (size_t)8 * 1024 * 1024);
    u16* rxb = xb  + (size_t)8388608;
    u16* Qb  = rxb + (size_t)8388608;
    u16* Kb  = Qb  + (size_t)8388608;
    u16* Vb  = Kb  + (size_t)8388608;
    u16* Ob  = Vb  + (size_t)8388608;

    rope_cast<<<16384, 256, 0, stream>>>(x, xb, rxb);
    wcast<<<16384, 256, 0, stream>>>(Wq, Wk, Wv, Wo, Wqb);

    dim3 g(64, 8);
    gemm128<0><<<g, 256, 0, stream>>>(rxb, Wqb, Qb, nullptr, nullptr);
    gemm128<0><<<g, 256, 0, stream>>>(rxb, Wkb, Kb, nullptr, nullptr);
    gemm128<0><<<g, 256, 0, stream>>>(xb,  Wvb, Vb, nullptr, nullptr);

    attn64<<<dim3(16, 64), 256, 0, stream>>>(Qb, Kb, Vb, Ob);

    gemm128<1><<<g, 256, 0, stream>>>(Ob, Wob, nullptr, (float*)d_out, bo);
}

// Round 8
// 372.753 us; speedup vs baseline: 1.4440x; 1.0362x over previous
//
#include <hip/hip_runtime.h>

// ---------- types ----------
typedef unsigned short u16;
typedef unsigned int   u32;
typedef __attribute__((ext_vector_type(4))) float f32x4;
typedef __attribute__((ext_vector_type(8))) __bf16 bf16x8;
typedef __attribute__((ext_vector_type(2))) u32  u32x2;
typedef __attribute__((ext_vector_type(4))) u32  u32x4;

#define LDS_CAST(p) ((__attribute__((address_space(3))) void*)(p))
#define GLB_CAST(p) ((const __attribute__((address_space(1))) void*)(p))

__device__ __forceinline__ void load_lds16(const void* g, void* l) {
    __builtin_amdgcn_global_load_lds(GLB_CAST(g), LDS_CAST(l), 16, 0, 0);
}

__device__ __forceinline__ u32 lds_off(const void* p) {
    return (u32)(size_t)(const __attribute__((address_space(3))) void*)p;
}

__device__ __forceinline__ u16 f2bf(float f) {
    union { float f; u32 u; } v; v.f = f;
    u32 r = (v.u + 0x7FFFu + ((v.u >> 16) & 1u)) >> 16;
    return (u16)r;
}

__device__ __forceinline__ u16 bfc(float f) {          // compiler cast (v_cvt_pk fusion)
    return __builtin_bit_cast(u16, (__bf16)f);
}
__device__ __forceinline__ u32 pack_bf16(float a, float b) {
    return (u32)bfc(a) | ((u32)bfc(b) << 16);
}

__device__ __forceinline__ float exp2fast(float x) {
#if __has_builtin(__builtin_amdgcn_exp2f)
    return __builtin_amdgcn_exp2f(x);
#else
    return __expf(x * 0.6931471805599453f);
#endif
}

// ---------- kernel 1: RoPE + cast ----------
__global__ __launch_bounds__(256) void rope_cast(const float* __restrict__ x,
                                                 u16* __restrict__ xb,
                                                 u16* __restrict__ rxb) {
    int idx = blockIdx.x * 256 + threadIdx.x;      // one pair, total 4194304
    int e2 = (idx & 511) * 2;
    int t  = (idx >> 9) & 2047;
    float2 v = *(const float2*)&x[(size_t)idx * 2];
    float theta = expf(-0.0089944730194981f * (float)e2);
    float angle = (float)t * theta;
    float sa, ca;
    sincosf(angle, &sa, &ca);
    float r0 = v.x * ca - v.y * sa;
    float r1 = v.y * ca + v.x * sa;
    u32 xp  = (u32)f2bf(v.x) | ((u32)f2bf(v.y) << 16);
    u32 rxp = (u32)f2bf(r0)  | ((u32)f2bf(r1)  << 16);
    *(u32*)&xb[(size_t)idx * 2]  = xp;
    *(u32*)&rxb[(size_t)idx * 2] = rxp;
}

// ---------- kernel 2: weight cast ----------
__global__ __launch_bounds__(256) void wcast(const float* __restrict__ a,
                                             const float* __restrict__ b,
                                             const float* __restrict__ c,
                                             const float* __restrict__ d,
                                             u16* __restrict__ out) {
    int i = blockIdx.x * 256 + threadIdx.x;        // 4M total
    int w = i >> 20, j = i & 1048575;
    float v = (w == 0) ? a[j] : (w == 1) ? b[j] : (w == 2) ? c[j] : d[j];
    out[i] = f2bf(v);
}

// ---------- kernel 3: GEMM  C = A @ W^T ----------
// MODE 0: merged QKV. W rows 0..3071 = [Wq;Wk;Wv]; A = (n0<2048)? rx : x.
//         Output remap into Q/K/V (B,H,T,64) blocks (contiguous 8M elems each).
// MODE 1: O-projection, fp32 out + bias.
template <int MODE>
__global__ __launch_bounds__(256) void gemm128(const u16* __restrict__ A0,
                                               const u16* __restrict__ A1,
                                               const u16* __restrict__ W,
                                               u16* __restrict__ outb,
                                               float* __restrict__ outf,
                                               const float* __restrict__ bias) {
    constexpr int Kd = 1024;
    __shared__ u16 As[128 * 64];
    __shared__ u16 Bs[128 * 64];
    const int tid = threadIdx.x;
    const int m0 = blockIdx.x * 128;
    const int n0 = blockIdx.y * 128;
    const u16* A = (MODE == 0 && n0 >= 2048) ? A1 : A0;
    const int wid = tid >> 6, lane = tid & 63;
    const int wr = wid >> 1, wc = wid & 1;
    const int lr = lane & 15, lhi = lane >> 4;

    f32x4 acc[4][4] = {};

    for (int k0 = 0; k0 < Kd; k0 += 64) {
        if (k0) __syncthreads();
#pragma unroll
        for (int i = 0; i < 4; ++i) {
            int cidx = tid + 256 * i;
            int row = cidx >> 3, col = (cidx & 7) * 8;
            load_lds16(A + (size_t)(m0 + row) * Kd + k0 + col, &As[row * 64 + col]);
        }
#pragma unroll
        for (int i = 0; i < 4; ++i) {
            int cidx = tid + 256 * i;
            int row = cidx >> 3, col = (cidx & 7) * 8;
            load_lds16(W + (size_t)(n0 + row) * Kd + k0 + col, &Bs[row * 64 + col]);
        }
        __syncthreads();
#pragma unroll
        for (int c = 0; c < 2; ++c) {
            bf16x8 a[4], b[4];
#pragma unroll
            for (int m = 0; m < 4; ++m)
                a[m] = *(const bf16x8*)&As[(wr * 64 + m * 16 + lr) * 64 + c * 32 + lhi * 8];
#pragma unroll
            for (int n = 0; n < 4; ++n)
                b[n] = *(const bf16x8*)&Bs[(wc * 64 + n * 16 + lr) * 64 + c * 32 + lhi * 8];
#pragma unroll
            for (int m = 0; m < 4; ++m)
#pragma unroll
                for (int n = 0; n < 4; ++n)
                    acc[m][n] = __builtin_amdgcn_mfma_f32_16x16x32_bf16(a[m], b[n], acc[m][n], 0, 0, 0);
        }
    }

#pragma unroll
    for (int m = 0; m < 4; ++m) {
        int rowb = m0 + wr * 64 + m * 16 + lhi * 4;
#pragma unroll
        for (int n = 0; n < 4; ++n) {
            int col = n0 + wc * 64 + n * 16 + lr;
#pragma unroll
            for (int r = 0; r < 4; ++r) {
                int mg = rowb + r;
                float v = acc[m][n][r];
                if (MODE == 0) {
                    int bb = mg >> 11, t = mg & 2047;
                    int hg = col >> 6, d = col & 63;   // hg 0..47
                    outb[(size_t)(hg >> 4) * 8388608 +
                         (((size_t)(bb * 16 + (hg & 15)) * 2048) + t) * 64 + d] = bfc(v);
                } else {
                    outf[(size_t)mg * 1024 + col] = v + bias[col];
                }
            }
        }
    }
}

// ---------- attention per-tile pass (one 16-row q-tile vs one 64-kv tile) ----------
// Scores computed in exp2 domain (Q pre-scaled by 0.125*log2e).
// P stored TRANSPOSED per wave: PT[64 kv][16 q] bf16 (rows 32B), written as
// ds_write_b64 (4 lanes' q-quad packed), read back as PV A-frag via
// ds_read_b64_tr_b16 (addr + j*32B walks kv at fixed q) — same HW model the
// self-check validates.
__device__ __forceinline__ void attn_pass(const bf16x8 (&qa)[2], f32x4 (&acc)[4],
                                          float (&m_i)[4], float (&l_i)[4],
                                          const u16* ks, const u16* vcur, u32 vsb,
                                          u16* pw, u32 ptb, int lr, int lhi,
                                          int kv0, int q0w, bool diag, bool use_tr) {
    // ---- QK^T ----
    f32x4 s4[4] = {};
    __builtin_amdgcn_s_setprio(1);
#pragma unroll
    for (int c = 0; c < 2; ++c)
#pragma unroll
        for (int n = 0; n < 4; ++n) {
            int r = n * 16 + lr;
            bf16x8 kb = *(const bf16x8*)&ks[r * 64 + ((c * 32 + lhi * 8) ^ ((r & 7) * 8))];
            s4[n] = __builtin_amdgcn_mfma_f32_16x16x32_bf16(qa[c], kb, s4[n], 0, 0, 0);
        }
    __builtin_amdgcn_s_setprio(0);

    // ---- mask (diagonal tile only) ----
    if (diag) {
#pragma unroll
        for (int n = 0; n < 4; ++n) {
            int kvg = kv0 + n * 16 + lr;
#pragma unroll
            for (int r = 0; r < 4; ++r)
                if (kvg > q0w + lhi * 4 + r) s4[n][r] = -1e30f;
        }
    }

    // ---- online softmax (exp2 domain) ----
    float mx[4] = { -1e30f, -1e30f, -1e30f, -1e30f };
#pragma unroll
    for (int n = 0; n < 4; ++n)
#pragma unroll
        for (int r = 0; r < 4; ++r) mx[r] = fmaxf(mx[r], s4[n][r]);
#pragma unroll
    for (int off = 8; off; off >>= 1)
#pragma unroll
        for (int r = 0; r < 4; ++r) mx[r] = fmaxf(mx[r], __shfl_xor(mx[r], off));

#pragma unroll
    for (int r = 0; r < 4; ++r) {
        float mnew = fmaxf(m_i[r], mx[r]);
        float sc = exp2fast(m_i[r] - mnew);
        m_i[r] = mnew;
        l_i[r] *= sc;
#pragma unroll
        for (int nd = 0; nd < 4; ++nd) acc[nd][r] *= sc;
    }
    float rs[4] = { 0.f, 0.f, 0.f, 0.f };
#pragma unroll
    for (int n = 0; n < 4; ++n) {
        float p0 = exp2fast(s4[n][0] - m_i[0]);
        float p1 = exp2fast(s4[n][1] - m_i[1]);
        float p2 = exp2fast(s4[n][2] - m_i[2]);
        float p3 = exp2fast(s4[n][3] - m_i[3]);
        rs[0] += p0; rs[1] += p1; rs[2] += p2; rs[3] += p3;
        u32x2 wv; wv.x = pack_bf16(p0, p1); wv.y = pack_bf16(p2, p3);
        *(u32x2*)&pw[(n * 16 + lr) * 16 + lhi * 4] = wv;   // PT row kv, cols q
    }
#pragma unroll
    for (int off = 8; off; off >>= 1)
#pragma unroll
        for (int r = 0; r < 4; ++r) rs[r] += __shfl_xor(rs[r], off);
#pragma unroll
    for (int r = 0; r < 4; ++r) l_i[r] += rs[r];

    // drain PT writes before asm tr-reads (compiler can't see the dependency)
    asm volatile("s_waitcnt lgkmcnt(0)" ::: "memory");

    // ---- P @ V ----
    __builtin_amdgcn_s_setprio(1);
#pragma unroll
    for (int c = 0; c < 2; ++c) {
        union { bf16x8 v; u32 w[4]; u16 h[8]; } pa;
        union { bf16x8 v; u32 w[4]; u16 h[8]; } vb[4];
        if (use_tr) {
            u32x2 plo, phi;
            u32 paddr = ptb + (u32)(c * 1024 + lhi * 256 + lr * 2);
            asm volatile("ds_read_b64_tr_b16 %0, %2\n\t"
                         "ds_read_b64_tr_b16 %1, %2 offset:128"
                         : "=&v"(plo), "=&v"(phi) : "v"(paddr));
            u32x2 lo[4], hi[4];
#pragma unroll
            for (int nd = 0; nd < 4; ++nd) {
                u32 a = vsb + (u32)((c * 32 + lhi * 8 + nd) * 128 + lr * 2);
                asm volatile("ds_read_b64_tr_b16 %0, %2\n\t"
                             "ds_read_b64_tr_b16 %1, %2 offset:512"
                             : "=&v"(lo[nd]), "=&v"(hi[nd]) : "v"(a));
            }
            asm volatile("s_waitcnt lgkmcnt(0)" ::: "memory");
            __builtin_amdgcn_sched_barrier(0);
            pa.w[0] = plo.x; pa.w[1] = plo.y; pa.w[2] = phi.x; pa.w[3] = phi.y;
#pragma unroll
            for (int nd = 0; nd < 4; ++nd) {
                vb[nd].w[0] = lo[nd].x; vb[nd].w[1] = lo[nd].y;
                vb[nd].w[2] = hi[nd].x; vb[nd].w[3] = hi[nd].y;
            }
        } else {
#pragma unroll
            for (int i = 0; i < 8; ++i) {
                int k = c * 32 + lhi * 8 + i;
                pa.h[i] = pw[k * 16 + lr];
#pragma unroll
                for (int nd = 0; nd < 4; ++nd)
                    vb[nd].h[i] = vcur[((k >> 2) << 8) + (nd << 6) + ((k & 3) << 4) + lr];
            }
        }
#pragma unroll
        for (int nd = 0; nd < 4; ++nd)
            acc[nd] = __builtin_amdgcn_mfma_f32_16x16x32_bf16(pa.v, vb[nd].v, acc[nd], 0, 0, 0);
    }
    __builtin_amdgcn_s_setprio(0);
}

// ---------- kernel 4: causal flash attention (v4 — paired + PT/exp2) ----------
__global__ __launch_bounds__(256) void attn64(const u16* __restrict__ Q,
                                              const u16* __restrict__ K,
                                              const u16* __restrict__ V,
                                              u16* __restrict__ O) {
    constexpr int T = 2048;
    __shared__ u16 Ks[2][64 * 64];
    __shared__ u16 Vs[2][64 * 64];
    __shared__ u16 Ps[4][64 * 16];     // per-wave PT: [kv][q]
    const int tid = threadIdx.x, wid = tid >> 6, lane = tid & 63;
    const int lr = lane & 15, lhi = lane >> 4;
    const int bh = blockIdx.y;
    const int qtA = blockIdx.x;            // 0..15
    const int qtB = 31 - qtA;              // 16..31
    const int q0wA = qtA * 64 + wid * 16;
    const int q0wB = qtB * 64 + wid * 16;
    const size_t base = (size_t)bh * T * 64;
    const u16* Qp = Q + base;
    const u16* Kp = K + base;
    const u16* Vp = V + base;

    // Q fragments, pre-scaled by 0.125 * log2(e) (exp2-domain softmax)
    const float QS = 0.18033688011112042f;
    bf16x8 qaA[2], qaB[2];
#pragma unroll
    for (int c = 0; c < 2; ++c) {
        bf16x8 tA = *(const bf16x8*)&Qp[(size_t)(q0wA + lr) * 64 + c * 32 + lhi * 8];
        bf16x8 tB = *(const bf16x8*)&Qp[(size_t)(q0wB + lr) * 64 + c * 32 + lhi * 8];
        bf16x8 oA, oB;
#pragma unroll
        for (int i = 0; i < 8; ++i) {
            oA[i] = (__bf16)((float)tA[i] * QS);
            oB[i] = (__bf16)((float)tB[i] * QS);
        }
        qaA[c] = oA; qaB[c] = oB;
    }

    f32x4 accA[4] = {}, accB[4] = {};
    float m_iA[4], l_iA[4], m_iB[4], l_iB[4];
#pragma unroll
    for (int r = 0; r < 4; ++r) {
        m_iA[r] = -1e30f; l_iA[r] = 0.f;
        m_iB[r] = -1e30f; l_iB[r] = 0.f;
    }

    // ---- one-time tr_read self-check: fill Vs[0] with value=index ----
    {
        u16* vt = (u16*)&Vs[0][0];
#pragma unroll
        for (int j = 0; j < 16; ++j) vt[tid * 16 + j] = (u16)(tid * 16 + j);
    }
    __syncthreads();
    bool use_tr;
    {
        const u32 vsb0 = lds_off(&Vs[0][0]);
        bool ok = true;
#pragma unroll
        for (int t = 0; t < 2; ++t) {
            const int c = t ? 1 : 0, nd = t ? 3 : 0;
            u32 a = vsb0 + (u32)((c * 32 + lhi * 8 + nd) * 128 + lr * 2);
            u32x2 lo, hi;
            asm volatile("ds_read_b64_tr_b16 %0, %2\n\t"
                         "ds_read_b64_tr_b16 %1, %2 offset:512"
                         : "=&v"(lo), "=&v"(hi) : "v"(a));
            asm volatile("s_waitcnt lgkmcnt(0)" ::: "memory");
            __builtin_amdgcn_sched_barrier(0);
            union { u32 w[4]; u16 h[8]; } u;
            u.w[0] = lo.x; u.w[1] = lo.y; u.w[2] = hi.x; u.w[3] = hi.y;
#pragma unroll
            for (int i = 0; i < 8; ++i) {
                int k = c * 32 + lhi * 8 + i;
                int e = ((k >> 2) << 8) + (nd << 6) + ((k & 3) << 4) + lr;
                ok = ok && (u.h[i] == (u16)e);
            }
        }
        use_tr = (bool)__all((int)ok);
    }
    __syncthreads();

    // ---- stage helper ----
#define STAGE(bb, kv0s)                                                          \
    {                                                                            \
        _Pragma("unroll")                                                        \
        for (int i = 0; i < 2; ++i) {                                            \
            int q = tid + 256 * i;                                               \
            int krow = q >> 3;                                                   \
            int kcol = ((q & 7) ^ (krow & 7)) * 8;                               \
            load_lds16(Kp + (size_t)((kv0s) + krow) * 64 + kcol, &Ks[bb][q * 8]);\
            int vk = ((q >> 5) << 2) + ((q >> 1) & 3);                           \
            int vd = (((q >> 3) & 3) << 4) + ((q & 1) << 3);                     \
            load_lds16(Vp + (size_t)((kv0s) + vk) * 64 + vd, &Vs[bb][q * 8]);    \
        }                                                                        \
    }

    STAGE(0, 0);
    __syncthreads();

    u16* pw = Ps[wid];
    const u32 ptb = lds_off(pw);
    int buf = 0;
    for (int kt = 0; kt <= qtB; ++kt) {
        const int kv0 = kt * 64;
        if (kt < qtB) STAGE(buf ^ 1, kv0 + 64);

        const u16* ks = Ks[buf];
        const u16* vcur = Vs[buf];
        const u32 vsb = lds_off(vcur);

        if (kt <= qtA)
            attn_pass(qaA, accA, m_iA, l_iA, ks, vcur, vsb, pw, ptb, lr, lhi,
                      kv0, q0wA, kt == qtA, use_tr);
        attn_pass(qaB, accB, m_iB, l_iB, ks, vcur, vsb, pw, ptb, lr, lhi,
                  kv0, q0wB, kt == qtB, use_tr);

        __syncthreads();
        buf ^= 1;
    }
#undef STAGE

    // ---- epilogue ----
    const int b = bh >> 4, h = bh & 15;
#pragma unroll
    for (int nd = 0; nd < 4; ++nd)
#pragma unroll
        for (int r = 0; r < 4; ++r) {
            int d = h * 64 + nd * 16 + lr;
            int qgA = q0wA + lhi * 4 + r;
            int qgB = q0wB + lhi * 4 + r;
            O[(size_t)(b * 2048 + qgA) * 1024 + d] = bfc(accA[nd][r] / l_iA[r]);
            O[(size_t)(b * 2048 + qgB) * 1024 + d] = bfc(accB[nd][r] / l_iB[r]);
        }
}

// ---------- launch ----------
extern "C" void kernel_launch(void* const* d_in, const int* in_sizes, int n_in,
                              void* d_out, int out_size, void* d_ws, size_t ws_size,
                              hipStream_t stream) {
    const float* x  = (const float*)d_in[0];
    const float* Wq = (const float*)d_in[1];
    const float* Wk = (const float*)d_in[2];
    const float* Wv = (const float*)d_in[3];
    const float* Wo = (const float*)d_in[4];
    const float* bo = (const float*)d_in[5];

    char* ws = (char*)d_ws;
    u16* Wqb = (u16*)ws;              // [Wq;Wk;Wv;Wo] bf16, 4M elems contiguous
    u16* Wob = Wqb + 3 * (1 << 20);
    u16* xb  = (u16*)(ws + (size_t)8 * 1024 * 1024);
    u16* rxb = xb  + (size_t)8388608;
    u16* Qb  = rxb + (size_t)8388608;   // Q,K,V contiguous 8M-elem blocks
    u16* Kb  = Qb  + (size_t)8388608;
    u16* Vb  = Kb  + (size_t)8388608;
    u16* Ob  = Vb  + (size_t)8388608;

    rope_cast<<<16384, 256, 0, stream>>>(x, xb, rxb);
    wcast<<<16384, 256, 0, stream>>>(Wq, Wk, Wv, Wo, Wqb);

    gemm128<0><<<dim3(64, 24), 256, 0, stream>>>(rxb, xb, Wqb, Qb, nullptr, nullptr);

    attn64<<<dim3(16, 64), 256, 0, stream>>>(Qb, Kb, Vb, Ob);

    gemm128<1><<<dim3(64, 8), 256, 0, stream>>>(Ob, Ob, Wob, nullptr, (float*)d_out, bo);
}

// Round 10
// 363.762 us; speedup vs baseline: 1.4797x; 1.0247x over previous
//
#include <hip/hip_runtime.h>

// ---------- types ----------
typedef unsigned short u16;
typedef unsigned int   u32;
typedef __attribute__((ext_vector_type(4))) float f32x4;
typedef __attribute__((ext_vector_type(8))) __bf16 bf16x8;
typedef __attribute__((ext_vector_type(2))) u32  u32x2;
typedef __attribute__((ext_vector_type(4))) u32  u32x4;

#define LDS_CAST(p) ((__attribute__((address_space(3))) void*)(p))
#define GLB_CAST(p) ((const __attribute__((address_space(1))) void*)(p))

__device__ __forceinline__ void load_lds16(const void* g, void* l) {
    __builtin_amdgcn_global_load_lds(GLB_CAST(g), LDS_CAST(l), 16, 0, 0);
}

__device__ __forceinline__ u32 lds_off(const void* p) {
    return (u32)(size_t)(const __attribute__((address_space(3))) void*)p;
}

__device__ __forceinline__ u16 f2bf(float f) {
    union { float f; u32 u; } v; v.f = f;
    u32 r = (v.u + 0x7FFFu + ((v.u >> 16) & 1u)) >> 16;
    return (u16)r;
}

__device__ __forceinline__ u16 bfc(float f) {          // compiler bf16 cast
    return __builtin_bit_cast(u16, (__bf16)f);
}

__device__ __forceinline__ float exp2fast(float x) {
#if __has_builtin(__builtin_amdgcn_exp2f)
    return __builtin_amdgcn_exp2f(x);
#else
    return __expf(x * 0.6931471805599453f);
#endif
}

// ---------- kernel 1: RoPE + cast ----------
__global__ __launch_bounds__(256) void rope_cast(const float* __restrict__ x,
                                                 u16* __restrict__ xb,
                                                 u16* __restrict__ rxb) {
    int idx = blockIdx.x * 256 + threadIdx.x;      // one pair, total 4194304
    int e2 = (idx & 511) * 2;
    int t  = (idx >> 9) & 2047;
    float2 v = *(const float2*)&x[(size_t)idx * 2];
    float theta = expf(-0.0089944730194981f * (float)e2);
    float angle = (float)t * theta;
    float sa, ca;
    sincosf(angle, &sa, &ca);
    float r0 = v.x * ca - v.y * sa;
    float r1 = v.y * ca + v.x * sa;
    u32 xp  = (u32)f2bf(v.x) | ((u32)f2bf(v.y) << 16);
    u32 rxp = (u32)f2bf(r0)  | ((u32)f2bf(r1)  << 16);
    *(u32*)&xb[(size_t)idx * 2]  = xp;
    *(u32*)&rxb[(size_t)idx * 2] = rxp;
}

// ---------- kernel 2: weight cast ----------
__global__ __launch_bounds__(256) void wcast(const float* __restrict__ a,
                                             const float* __restrict__ b,
                                             const float* __restrict__ c,
                                             const float* __restrict__ d,
                                             u16* __restrict__ out) {
    int i = blockIdx.x * 256 + threadIdx.x;        // 4M total
    int w = i >> 20, j = i & 1048575;
    float v = (w == 0) ? a[j] : (w == 1) ? b[j] : (w == 2) ? c[j] : d[j];
    out[i] = f2bf(v);
}

// ---------- kernel 3: GEMM  C = A @ W^T ----------
// MODE 0: merged QKV. W rows 0..3071 = [Wq;Wk;Wv]; A = (n0<2048)? rx : x.
//         Output remap into Q/K/V (B,H,T,64) blocks (contiguous 8M elems each).
// MODE 1: O-projection, fp32 out + bias.
template <int MODE>
__global__ __launch_bounds__(256) void gemm128(const u16* __restrict__ A0,
                                               const u16* __restrict__ A1,
                                               const u16* __restrict__ W,
                                               u16* __restrict__ outb,
                                               float* __restrict__ outf,
                                               const float* __restrict__ bias) {
    constexpr int Kd = 1024;
    __shared__ u16 As[128 * 64];
    __shared__ u16 Bs[128 * 64];
    const int tid = threadIdx.x;
    const int m0 = blockIdx.x * 128;
    const int n0 = blockIdx.y * 128;
    const u16* A = (MODE == 0 && n0 >= 2048) ? A1 : A0;
    const int wid = tid >> 6, lane = tid & 63;
    const int wr = wid >> 1, wc = wid & 1;
    const int lr = lane & 15, lhi = lane >> 4;

    f32x4 acc[4][4] = {};

    for (int k0 = 0; k0 < Kd; k0 += 64) {
        if (k0) __syncthreads();
#pragma unroll
        for (int i = 0; i < 4; ++i) {
            int cidx = tid + 256 * i;
            int row = cidx >> 3, col = (cidx & 7) * 8;
            load_lds16(A + (size_t)(m0 + row) * Kd + k0 + col, &As[row * 64 + col]);
        }
#pragma unroll
        for (int i = 0; i < 4; ++i) {
            int cidx = tid + 256 * i;
            int row = cidx >> 3, col = (cidx & 7) * 8;
            load_lds16(W + (size_t)(n0 + row) * Kd + k0 + col, &Bs[row * 64 + col]);
        }
        __syncthreads();
#pragma unroll
        for (int c = 0; c < 2; ++c) {
            bf16x8 a[4], b[4];
#pragma unroll
            for (int m = 0; m < 4; ++m)
                a[m] = *(const bf16x8*)&As[(wr * 64 + m * 16 + lr) * 64 + c * 32 + lhi * 8];
#pragma unroll
            for (int n = 0; n < 4; ++n)
                b[n] = *(const bf16x8*)&Bs[(wc * 64 + n * 16 + lr) * 64 + c * 32 + lhi * 8];
#pragma unroll
            for (int m = 0; m < 4; ++m)
#pragma unroll
                for (int n = 0; n < 4; ++n)
                    acc[m][n] = __builtin_amdgcn_mfma_f32_16x16x32_bf16(a[m], b[n], acc[m][n], 0, 0, 0);
        }
    }

#pragma unroll
    for (int m = 0; m < 4; ++m) {
        int rowb = m0 + wr * 64 + m * 16 + lhi * 4;
#pragma unroll
        for (int n = 0; n < 4; ++n) {
            int col = n0 + wc * 64 + n * 16 + lr;
#pragma unroll
            for (int r = 0; r < 4; ++r) {
                int mg = rowb + r;
                float v = acc[m][n][r];
                if (MODE == 0) {
                    int bb = mg >> 11, t = mg & 2047;
                    int hg = col >> 6, d = col & 63;   // hg 0..47
                    outb[(size_t)(hg >> 4) * 8388608 +
                         (((size_t)(bb * 16 + (hg & 15)) * 2048) + t) * 64 + d] = bfc(v);
                } else {
                    outf[(size_t)mg * 1024 + col] = v + bias[col];
                }
            }
        }
    }
}

// ---------- attention per-tile pass (one 16-row q-tile vs one 64-kv tile) ----------
// exp2-domain softmax (Q pre-scaled by 0.125*log2e).
// P: per-wave 16x64 LDS, XOR-swizzled scalar stores + swizzled b128 reads (v3 form).
// V: subtiled LDS read via ds_read_b64_tr_b16 (self-check validated).
// T13 defer-max: skip rescale when max growth <= 8 (exp2 domain, P <= 256).
__device__ __forceinline__ void attn_pass(const bf16x8 (&qa)[2], f32x4 (&acc)[4],
                                          float (&m_i)[4], float (&l_i)[4],
                                          const u16* ks, const u16* vcur, u32 vsb,
                                          u16* pw, int lr, int lhi,
                                          int kv0, int q0w, bool diag, bool use_tr) {
    // ---- QK^T ----
    f32x4 s4[4] = {};
    __builtin_amdgcn_s_setprio(1);
#pragma unroll
    for (int c = 0; c < 2; ++c)
#pragma unroll
        for (int n = 0; n < 4; ++n) {
            int r = n * 16 + lr;
            bf16x8 kb = *(const bf16x8*)&ks[r * 64 + ((c * 32 + lhi * 8) ^ ((r & 7) * 8))];
            s4[n] = __builtin_amdgcn_mfma_f32_16x16x32_bf16(qa[c], kb, s4[n], 0, 0, 0);
        }
    __builtin_amdgcn_s_setprio(0);

    // ---- mask (diagonal tile only) ----
    if (diag) {
#pragma unroll
        for (int n = 0; n < 4; ++n) {
            int kvg = kv0 + n * 16 + lr;
#pragma unroll
            for (int r = 0; r < 4; ++r)
                if (kvg > q0w + lhi * 4 + r) s4[n][r] = -1e30f;
        }
    }

    // ---- tile row max ----
    float mx[4] = { -1e30f, -1e30f, -1e30f, -1e30f };
#pragma unroll
    for (int n = 0; n < 4; ++n)
#pragma unroll
        for (int r = 0; r < 4; ++r) mx[r] = fmaxf(mx[r], s4[n][r]);
#pragma unroll
    for (int off = 8; off; off >>= 1)
#pragma unroll
        for (int r = 0; r < 4; ++r) mx[r] = fmaxf(mx[r], __shfl_xor(mx[r], off));

    // ---- defer-max (T13): rescale only when max grew past threshold ----
    bool up = false;
#pragma unroll
    for (int r = 0; r < 4; ++r) up = up || (mx[r] > m_i[r] + 8.0f);
    if (__any((int)up)) {
#pragma unroll
        for (int r = 0; r < 4; ++r) {
            float mnew = fmaxf(m_i[r], mx[r]);
            float sc = exp2fast(m_i[r] - mnew);
            m_i[r] = mnew;
            l_i[r] *= sc;
#pragma unroll
            for (int nd = 0; nd < 4; ++nd) acc[nd][r] *= sc;
        }
    }

    // ---- P = exp2(S - m), swizzled store; row sums ----
    float rs[4] = { 0.f, 0.f, 0.f, 0.f };
#pragma unroll
    for (int n = 0; n < 4; ++n)
#pragma unroll
        for (int r = 0; r < 4; ++r) {
            float pv = exp2fast(s4[n][r] - m_i[r]);
            rs[r] += pv;
            int qloc = lhi * 4 + r;
            pw[qloc * 64 + ((n * 16 + lr) ^ ((qloc & 7) * 8))] = bfc(pv);
        }
#pragma unroll
    for (int off = 8; off; off >>= 1)
#pragma unroll
        for (int r = 0; r < 4; ++r) rs[r] += __shfl_xor(rs[r], off);
#pragma unroll
    for (int r = 0; r < 4; ++r) l_i[r] += rs[r];

    // ---- P @ V ----
    __builtin_amdgcn_s_setprio(1);
#pragma unroll
    for (int c = 0; c < 2; ++c) {
        bf16x8 pa = *(const bf16x8*)&pw[lr * 64 + ((c * 32 + lhi * 8) ^ ((lr & 7) * 8))];
        union { bf16x8 v; u32 w[4]; u16 h[8]; } vb[4];
        if (use_tr) {
            u32x2 lo[4], hi[4];
#pragma unroll
            for (int nd = 0; nd < 4; ++nd) {
                u32 a = vsb + (u32)((c * 32 + lhi * 8 + nd) * 128 + lr * 2);
                asm volatile("ds_read_b64_tr_b16 %0, %2\n\t"
                             "ds_read_b64_tr_b16 %1, %2 offset:512"
                             : "=&v"(lo[nd]), "=&v"(hi[nd]) : "v"(a));
            }
            asm volatile("s_waitcnt lgkmcnt(0)" ::: "memory");
            __builtin_amdgcn_sched_barrier(0);
#pragma unroll
            for (int nd = 0; nd < 4; ++nd) {
                vb[nd].w[0] = lo[nd].x; vb[nd].w[1] = lo[nd].y;
                vb[nd].w[2] = hi[nd].x; vb[nd].w[3] = hi[nd].y;
            }
        } else {
#pragma unroll
            for (int nd = 0; nd < 4; ++nd)
#pragma unroll
                for (int i = 0; i < 8; ++i) {
                    int k = c * 32 + lhi * 8 + i;
                    vb[nd].h[i] = vcur[((k >> 2) << 8) + (nd << 6) + ((k & 3) << 4) + lr];
                }
        }
#pragma unroll
        for (int nd = 0; nd < 4; ++nd)
            acc[nd] = __builtin_amdgcn_mfma_f32_16x16x32_bf16(pa, vb[nd].v, acc[nd], 0, 0, 0);
    }
    __builtin_amdgcn_s_setprio(0);
}

// ---------- kernel 4: causal flash attention (v5 — paired, v3-P, exp2, defer-max) ----------
__global__ __launch_bounds__(256) void attn64(const u16* __restrict__ Q,
                                              const u16* __restrict__ K,
                                              const u16* __restrict__ V,
                                              u16* __restrict__ O) {
    constexpr int T = 2048;
    __shared__ u16 Ks[2][64 * 64];
    __shared__ u16 Vs[2][64 * 64];
    __shared__ u16 Ps[4][16 * 64];     // per-wave P, swizzled
    const int tid = threadIdx.x, wid = tid >> 6, lane = tid & 63;
    const int lr = lane & 15, lhi = lane >> 4;
    const int bh = blockIdx.y;
    const int qtA = blockIdx.x;            // 0..15
    const int qtB = 31 - qtA;              // 16..31
    const int q0wA = qtA * 64 + wid * 16;
    const int q0wB = qtB * 64 + wid * 16;
    const size_t base = (size_t)bh * T * 64;
    const u16* Qp = Q + base;
    const u16* Kp = K + base;
    const u16* Vp = V + base;

    // Q fragments, pre-scaled by 0.125 * log2(e) (exp2-domain softmax)
    const float QS = 0.18033688011112042f;
    bf16x8 qaA[2], qaB[2];
#pragma unroll
    for (int c = 0; c < 2; ++c) {
        bf16x8 tA = *(const bf16x8*)&Qp[(size_t)(q0wA + lr) * 64 + c * 32 + lhi * 8];
        bf16x8 tB = *(const bf16x8*)&Qp[(size_t)(q0wB + lr) * 64 + c * 32 + lhi * 8];
        bf16x8 oA, oB;
#pragma unroll
        for (int i = 0; i < 8; ++i) {
            oA[i] = (__bf16)((float)tA[i] * QS);
            oB[i] = (__bf16)((float)tB[i] * QS);
        }
        qaA[c] = oA; qaB[c] = oB;
    }

    f32x4 accA[4] = {}, accB[4] = {};
    float m_iA[4], l_iA[4], m_iB[4], l_iB[4];
#pragma unroll
    for (int r = 0; r < 4; ++r) {
        m_iA[r] = -1e30f; l_iA[r] = 0.f;
        m_iB[r] = -1e30f; l_iB[r] = 0.f;
    }

    // ---- one-time tr_read self-check: fill Vs[0] with value=index ----
    {
        u16* vt = (u16*)&Vs[0][0];
#pragma unroll
        for (int j = 0; j < 16; ++j) vt[tid * 16 + j] = (u16)(tid * 16 + j);
    }
    __syncthreads();
    bool use_tr;
    {
        const u32 vsb0 = lds_off(&Vs[0][0]);
        bool ok = true;
#pragma unroll
        for (int t = 0; t < 2; ++t) {
            const int c = t ? 1 : 0, nd = t ? 3 : 0;
            u32 a = vsb0 + (u32)((c * 32 + lhi * 8 + nd) * 128 + lr * 2);
            u32x2 lo, hi;
            asm volatile("ds_read_b64_tr_b16 %0, %2\n\t"
                         "ds_read_b64_tr_b16 %1, %2 offset:512"
                         : "=&v"(lo), "=&v"(hi) : "v"(a));
            asm volatile("s_waitcnt lgkmcnt(0)" ::: "memory");
            __builtin_amdgcn_sched_barrier(0);
            union { u32 w[4]; u16 h[8]; } u;
            u.w[0] = lo.x; u.w[1] = lo.y; u.w[2] = hi.x; u.w[3] = hi.y;
#pragma unroll
            for (int i = 0; i < 8; ++i) {
                int k = c * 32 + lhi * 8 + i;
                int e = ((k >> 2) << 8) + (nd << 6) + ((k & 3) << 4) + lr;
                ok = ok && (u.h[i] == (u16)e);
            }
        }
        use_tr = (bool)__all((int)ok);
    }
    __syncthreads();

    // ---- stage helper ----
#define STAGE(bb, kv0s)                                                          \
    {                                                                            \
        _Pragma("unroll")                                                        \
        for (int i = 0; i < 2; ++i) {                                            \
            int q = tid + 256 * i;                                               \
            int krow = q >> 3;                                                   \
            int kcol = ((q & 7) ^ (krow & 7)) * 8;                               \
            load_lds16(Kp + (size_t)((kv0s) + krow) * 64 + kcol, &Ks[bb][q * 8]);\
            int vk = ((q >> 5) << 2) + ((q >> 1) & 3);                           \
            int vd = (((q >> 3) & 3) << 4) + ((q & 1) << 3);                     \
            load_lds16(Vp + (size_t)((kv0s) + vk) * 64 + vd, &Vs[bb][q * 8]);    \
        }                                                                        \
    }

    STAGE(0, 0);
    __syncthreads();

    u16* pw = Ps[wid];
    int buf = 0;
    for (int kt = 0; kt <= qtB; ++kt) {
        const int kv0 = kt * 64;
        if (kt < qtB) STAGE(buf ^ 1, kv0 + 64);

        const u16* ks = Ks[buf];
        const u16* vcur = Vs[buf];
        const u32 vsb = lds_off(vcur);

        if (kt <= qtA)
            attn_pass(qaA, accA, m_iA, l_iA, ks, vcur, vsb, pw, lr, lhi,
                      kv0, q0wA, kt == qtA, use_tr);
        attn_pass(qaB, accB, m_iB, l_iB, ks, vcur, vsb, pw, lr, lhi,
                  kv0, q0wB, kt == qtB, use_tr);

        __syncthreads();
        buf ^= 1;
    }
#undef STAGE

    // ---- epilogue ----
    const int b = bh >> 4, h = bh & 15;
#pragma unroll
    for (int nd = 0; nd < 4; ++nd)
#pragma unroll
        for (int r = 0; r < 4; ++r) {
            int d = h * 64 + nd * 16 + lr;
            int qgA = q0wA + lhi * 4 + r;
            int qgB = q0wB + lhi * 4 + r;
            O[(size_t)(b * 2048 + qgA) * 1024 + d] = bfc(accA[nd][r] / l_iA[r]);
            O[(size_t)(b * 2048 + qgB) * 1024 + d] = bfc(accB[nd][r] / l_iB[r]);
        }
}

// ---------- launch ----------
extern "C" void kernel_launch(void* const* d_in, const int* in_sizes, int n_in,
                              void* d_out, int out_size, void* d_ws, size_t ws_size,
                              hipStream_t stream) {
    const float* x  = (const float*)d_in[0];
    const float* Wq = (const float*)d_in[1];
    const float* Wk = (const float*)d_in[2];
    const float* Wv = (const float*)d_in[3];
    const float* Wo = (const float*)d_in[4];
    const float* bo = (const float*)d_in[5];

    char* ws = (char*)d_ws;
    u16* Wqb = (u16*)ws;              // [Wq;Wk;Wv;Wo] bf16, 4M elems contiguous
    u16* Wob = Wqb + 3 * (1 << 20);
    u16* xb  = (u16*)(ws + (size_t)8 * 1024 * 1024);
    u16* rxb = xb  + (size_t)8388608;
    u16* Qb  = rxb + (size_t)8388608;   // Q,K,V contiguous 8M-elem blocks
    u16* Kb  = Qb  + (size_t)8388608;
    u16* Vb  = Kb  + (size_t)8388608;
    u16* Ob  = Vb  + (size_t)8388608;

    rope_cast<<<16384, 256, 0, stream>>>(x, xb, rxb);
    wcast<<<16384, 256, 0, stream>>>(Wq, Wk, Wv, Wo, Wqb);

    gemm128<0><<<dim3(64, 24), 256, 0, stream>>>(rxb, xb, Wqb, Qb, nullptr, nullptr);

    attn64<<<dim3(16, 64), 256, 0, stream>>>(Qb, Kb, Vb, Ob);

    gemm128<1><<<dim3(64, 8), 256, 0, stream>>>(Ob, Ob, Wob, nullptr, (float*)d_out, bo);
}